// Round 2
// baseline (337.207 us; speedup 1.0000x reference)
//
#include <hip/hip_runtime.h>
#include <hip/hip_bf16.h>
#include <math.h>

#define DIMC 384
#define NH 6
#define HD 64
#define MLPD 1536
#define BS 8
#define SEQ 1024
#define T_TOK (BS*SEQ)                  // 8192 tokens
#define TC ((size_t)T_TOK*DIMC)         // 3,145,728 elems
#define QK_SCALE 0.125f                 // 64^-0.5

typedef __bf16 bf16;
typedef bf16 bf16x4 __attribute__((ext_vector_type(4)));
typedef bf16 bf16x8 __attribute__((ext_vector_type(8)));
typedef float floatx4 __attribute__((ext_vector_type(4)));

// ---------- fp32 -> bf16 weight conversion (qkv_w | proj_w | w1 | w2 contiguous) ----------
__global__ __launch_bounds__(256)
void cvt_all(const float* __restrict__ s0, const float* __restrict__ s1,
             const float* __restrict__ s2, const float* __restrict__ s3,
             bf16* __restrict__ dst) {
    int i = blockIdx.x * 256 + threadIdx.x;   // i < 442368 float4 chunks
    const int n0 = 110592, n1 = 36864, n2 = 147456;   // float4 counts
    const float4* src; int j;
    if (i < n0)           { src = (const float4*)s0; j = i; }
    else if (i < n0+n1)   { src = (const float4*)s1; j = i - n0; }
    else if (i < n0+n1+n2){ src = (const float4*)s2; j = i - n0 - n1; }
    else                  { src = (const float4*)s3; j = i - n0 - n1 - n2; }
    float4 v = src[j];
    bf16x4 o; o[0] = (bf16)v.x; o[1] = (bf16)v.y; o[2] = (bf16)v.z; o[3] = (bf16)v.w;
    ((bf16x4*)dst)[i] = o;
}

// ---------------- LayerNorm: one wave per token row (384 elems), fp32 in, bf16 out ----------
__global__ __launch_bounds__(64)
void ln_kernel(const float* __restrict__ x, const float* __restrict__ w,
               const float* __restrict__ b, bf16* __restrict__ out) {
    int row = blockIdx.x;
    int t = threadIdx.x;
    const float* xr = x + (size_t)row * DIMC;
    float vals[6];
    float s = 0.f;
    #pragma unroll
    for (int i = 0; i < 6; i++) { vals[i] = xr[t + i*64]; s += vals[i]; }
    #pragma unroll
    for (int m = 32; m; m >>= 1) s += __shfl_xor(s, m);
    float mean = s * (1.0f / DIMC);
    float sq = 0.f;
    #pragma unroll
    for (int i = 0; i < 6; i++) { float d = vals[i] - mean; sq += d * d; }
    #pragma unroll
    for (int m = 32; m; m >>= 1) sq += __shfl_xor(sq, m);
    float rstd = rsqrtf(sq * (1.0f / DIMC) + 1e-5f);
    bf16* orow = out + (size_t)row * DIMC;
    #pragma unroll
    for (int i = 0; i < 6; i++) {
        int c = t + i*64;
        orow[c] = (bf16)((vals[i] - mean) * rstd * w[c] + b[c]);
    }
}

// ---------------- GEMM: C[M,N] = A[M,K] @ W[N,K]^T, bf16 MFMA ----------------
// block = 4 waves (2x2), each wave 64x64 -> block tile 128x128.
// A-frag: A[row=lane&15][k=quad*8+j]; B-frag: W[col=lane&15][k=quad*8+j]
// C/D: col=lane&15, row=quad*4+reg  (verified layouts, m89/m91)
enum { EPI_QKV = 1, EPI_RES = 2, EPI_GELU = 3 };

template<int EPI, typename OutT>
__global__ __launch_bounds__(256)
void gemm_bt(const bf16* __restrict__ A, const bf16* __restrict__ W,
             const float* __restrict__ bias, const float* res,
             OutT* out, int M, int N, int K) {
    int lane = threadIdx.x & 63;
    int w = threadIdx.x >> 6;
    int quad = lane >> 4, l16 = lane & 15;
    int rbase = blockIdx.y * 128 + (w >> 1) * 64;
    int cbase = blockIdx.x * 128 + (w & 1) * 64;
    floatx4 acc[4][4] = {};
    for (int k0 = 0; k0 < K; k0 += 32) {
        bf16x8 a[4], bf[4];
        #pragma unroll
        for (int tm = 0; tm < 4; tm++)
            a[tm] = *(const bf16x8*)(A + (size_t)(rbase + tm*16 + l16) * K + k0 + quad*8);
        #pragma unroll
        for (int tn = 0; tn < 4; tn++)
            bf[tn] = *(const bf16x8*)(W + (size_t)(cbase + tn*16 + l16) * K + k0 + quad*8);
        #pragma unroll
        for (int tm = 0; tm < 4; tm++)
            #pragma unroll
            for (int tn = 0; tn < 4; tn++)
                acc[tm][tn] = __builtin_amdgcn_mfma_f32_16x16x32_bf16(a[tm], bf[tn], acc[tm][tn], 0, 0, 0);
    }
    #pragma unroll
    for (int tm = 0; tm < 4; tm++)
        #pragma unroll
        for (int tn = 0; tn < 4; tn++)
            #pragma unroll
            for (int r = 0; r < 4; r++) {
                int row = rbase + tm*16 + quad*4 + r;
                int col = cbase + tn*16 + l16;
                float v = acc[tm][tn][r];
                if (EPI == EPI_QKV) {
                    // col in [0,1152): which=col/384, h=(col%384)/64, d=col%64
                    int which = col / 384, rem = col % 384;
                    int hh = rem >> 6, d = rem & 63;
                    int bb = row >> 10, n = row & 1023;
                    out[(size_t)which * TC + (((size_t)(bb*NH + hh) * SEQ + n) << 6) + d] = (OutT)v;
                } else {
                    v += bias[col];
                    if (EPI == EPI_RES)  v += res[(size_t)row * N + col];
                    if (EPI == EPI_GELU) v = 0.5f * v * (1.0f + erff(v * 0.70710678118f));
                    out[(size_t)row * N + col] = (OutT)v;
                }
            }
}

// ---------------- Fused L2Q attention (flash-style, no NxN materialized) --------
// grid: (SEQ/128, B*H); block = 2 waves, each wave owns 64 Q rows.
// weights are relu(poly) >= 0 -> online accumulation without max-rescaling.
__global__ __launch_bounds__(128)
void attn_kernel(const bf16* __restrict__ q, const bf16* __restrict__ k,
                 const bf16* __restrict__ v, const float* __restrict__ alpha,
                 const float* __restrict__ beta, const float* __restrict__ gamma,
                 bf16* __restrict__ attn_out) {
    __shared__ bf16 Ksh[64][72];       // K tile [key][d], +8 pad
    __shared__ bf16 VTsh[64][72];      // V tile transposed [d][key]
    __shared__ bf16 Psh[2][64][72];    // per-wave P round-trip buffer
    int bh = blockIdx.y;
    int bb = bh / NH, h = bh % NH;
    int qbase = blockIdx.x * 128;
    int tid = threadIdx.x;
    int w = tid >> 6, lane = tid & 63, quad = lane >> 4, l16 = lane & 15;
    float av = alpha[h], bv = beta[h], gv = gamma[h];
    const bf16* qb = q + (size_t)bh * SEQ * HD;
    const bf16* kb = k + (size_t)bh * SEQ * HD;
    const bf16* vb = v + (size_t)bh * SEQ * HD;

    bf16x8 qa[4][2];
    #pragma unroll
    for (int tm = 0; tm < 4; tm++)
        #pragma unroll
        for (int ks = 0; ks < 2; ks++)
            qa[tm][ks] = *(const bf16x8*)(qb + (size_t)(qbase + w*64 + tm*16 + l16) * HD + ks*32 + quad*8);

    floatx4 o[4][4] = {};
    float rs[4][4] = {};

    for (int kt = 0; kt < SEQ / 64; kt++) {
        int kb0 = kt * 64;
        __syncthreads();   // prev iteration's LDS reads done
        #pragma unroll
        for (int c = 0; c < 4; c++) {
            int chunk = c * 128 + tid;       // 512 chunks of 8 bf16
            int r = chunk >> 3, c8 = (chunk & 7) * 8;
            *(bf16x8*)&Ksh[r][c8] = *(const bf16x8*)(kb + (size_t)(kb0 + r) * HD + c8);
            bf16x8 vv = *(const bf16x8*)(vb + (size_t)(kb0 + r) * HD + c8);
            #pragma unroll
            for (int j = 0; j < 8; j++) VTsh[c8 + j][r] = vv[j];
        }
        __syncthreads();
        // S = Q @ K^T  (64x64 per wave)
        floatx4 s[4][4] = {};
        #pragma unroll
        for (int ks = 0; ks < 2; ks++) {
            bf16x8 kf[4];
            #pragma unroll
            for (int tn = 0; tn < 4; tn++)
                kf[tn] = *(const bf16x8*)&Ksh[tn*16 + l16][ks*32 + quad*8];
            #pragma unroll
            for (int tm = 0; tm < 4; tm++)
                #pragma unroll
                for (int tn = 0; tn < 4; tn++)
                    s[tm][tn] = __builtin_amdgcn_mfma_f32_16x16x32_bf16(qa[tm][ks], kf[tn], s[tm][tn], 0, 0, 0);
        }
        // poly + relu + row-sum accumulate
        #pragma unroll
        for (int tm = 0; tm < 4; tm++)
            #pragma unroll
            for (int r = 0; r < 4; r++) {
                float part = 0.f;
                #pragma unroll
                for (int tn = 0; tn < 4; tn++) {
                    float xx = s[tm][tn][r] * QK_SCALE;
                    float p = fmaxf(av*xx*xx + bv*xx + gv, 0.f);
                    s[tm][tn][r] = p;
                    part += p;
                }
                #pragma unroll
                for (int m = 8; m; m >>= 1) part += __shfl_xor(part, m);  // sum 16 lanes in quad
                rs[tm][r] += part;
            }
        // P: C-layout -> LDS -> A-layout
        #pragma unroll
        for (int tm = 0; tm < 4; tm++)
            #pragma unroll
            for (int tn = 0; tn < 4; tn++)
                #pragma unroll
                for (int r = 0; r < 4; r++)
                    Psh[w][tm*16 + quad*4 + r][tn*16 + l16] = (bf16)s[tm][tn][r];
        __syncthreads();
        // O += P @ V
        #pragma unroll
        for (int ks = 0; ks < 2; ks++) {
            bf16x8 vf[4], pf[4];
            #pragma unroll
            for (int tn = 0; tn < 4; tn++)
                vf[tn] = *(const bf16x8*)&VTsh[tn*16 + l16][ks*32 + quad*8];
            #pragma unroll
            for (int tm = 0; tm < 4; tm++)
                pf[tm] = *(const bf16x8*)&Psh[w][tm*16 + l16][ks*32 + quad*8];
            #pragma unroll
            for (int tm = 0; tm < 4; tm++)
                #pragma unroll
                for (int tn = 0; tn < 4; tn++)
                    o[tm][tn] = __builtin_amdgcn_mfma_f32_16x16x32_bf16(pf[tm], vf[tn], o[tm][tn], 0, 0, 0);
        }
    }
    // normalize and write to [B,N,C] layout for proj GEMM
    #pragma unroll
    for (int tm = 0; tm < 4; tm++)
        #pragma unroll
        for (int tn = 0; tn < 4; tn++)
            #pragma unroll
            for (int r = 0; r < 4; r++) {
                int n = qbase + w*64 + tm*16 + quad*4 + r;
                float val = o[tm][tn][r] / (rs[tm][r] + 1e-6f);
                attn_out[((size_t)(bb*SEQ + n)) * DIMC + h*HD + tn*16 + l16] = (bf16)val;
            }
}

// ---------------- driver ----------------
extern "C" void kernel_launch(void* const* d_in, const int* in_sizes, int n_in,
                              void* d_out, int out_size, void* d_ws, size_t ws_size,
                              hipStream_t stream) {
    const float* x      = (const float*)d_in[0];
    const float* qkv_w  = (const float*)d_in[1];
    const float* proj_w = (const float*)d_in[2];
    const float* proj_b = (const float*)d_in[3];
    const float* alpha  = (const float*)d_in[4];
    const float* beta   = (const float*)d_in[5];
    const float* gamma  = (const float*)d_in[6];
    const float* ln1_w  = (const float*)d_in[7];
    const float* ln1_b  = (const float*)d_in[8];
    const float* ln2_w  = (const float*)d_in[9];
    const float* ln2_b  = (const float*)d_in[10];
    const float* w1     = (const float*)d_in[11];
    const float* b1     = (const float*)d_in[12];
    const float* w2     = (const float*)d_in[13];
    const float* b2     = (const float*)d_in[14];
    float* out = (float*)d_out;           // fp32 output; also doubles as x1 buffer

    // ws layout (bytes):
    //   [0, 3538944)            bf16 weights: qkv_w(442368) proj_w(147456) w1(589824) w2(589824)
    //   [3538944, 9830400)      h (TC bf16) — ln1 out, later ln2 out
    //   [9830400, 28704768)     qkv (3*TC bf16) — overlaid by m (4*TC bf16) later
    //   [28704768, 34996224)    attn_out (TC bf16) — tail of m overlay
    char* base = (char*)d_ws;
    bf16* wq_bf = (bf16*)base;                 // 1152x384
    bf16* wp_bf = wq_bf + 442368;              // 384x384
    bf16* w1_bf = wq_bf + 589824;              // 1536x384
    bf16* w2_bf = wq_bf + 1179648;             // 384x1536
    bf16* h        = (bf16*)(base + 3538944);
    bf16* qkv      = (bf16*)(base + 9830400);
    bf16* attn_o   = (bf16*)(base + 28704768);
    bf16* m        = qkv;                      // 4*TC, overlays qkv+attn_o (both dead by then)

    cvt_all<<<1728, 256, 0, stream>>>(qkv_w, proj_w, w1, w2, wq_bf);
    ln_kernel<<<T_TOK, 64, 0, stream>>>(x, ln1_w, ln1_b, h);
    gemm_bt<EPI_QKV, bf16><<<dim3(1152/128, T_TOK/128), 256, 0, stream>>>(
        h, wq_bf, nullptr, nullptr, qkv, T_TOK, 1152, DIMC);
    attn_kernel<<<dim3(SEQ/128, BS*NH), 128, 0, stream>>>(
        qkv, qkv + TC, qkv + 2*TC, alpha, beta, gamma, attn_o);
    gemm_bt<EPI_RES, float><<<dim3(DIMC/128, T_TOK/128), 256, 0, stream>>>(
        attn_o, wp_bf, proj_b, x, out /*x1*/, T_TOK, DIMC, DIMC);
    ln_kernel<<<T_TOK, 64, 0, stream>>>(out /*x1*/, ln2_w, ln2_b, h);
    gemm_bt<EPI_GELU, bf16><<<dim3(MLPD/128, T_TOK/128), 256, 0, stream>>>(
        h, w1_bf, b1, nullptr, m, T_TOK, MLPD, DIMC);
    gemm_bt<EPI_RES, float><<<dim3(DIMC/128, T_TOK/128), 256, 0, stream>>>(
        m, w2_bf, b2, out /*x1 (read-then-write in place, same element)*/, out, T_TOK, DIMC, MLPD);
}

// Round 3
// 327.440 us; speedup vs baseline: 1.0298x; 1.0298x over previous
//
#include <hip/hip_runtime.h>
#include <hip/hip_bf16.h>
#include <math.h>

#define DIMC 384
#define NH 6
#define HD 64
#define MLPD 1536
#define BS 8
#define SEQ 1024
#define T_TOK (BS*SEQ)                  // 8192 tokens
#define TC ((size_t)T_TOK*DIMC)         // 3,145,728 elems
#define QK_SCALE 0.125f                 // 64^-0.5

typedef __bf16 bf16;
typedef bf16 bf16x4 __attribute__((ext_vector_type(4)));
typedef bf16 bf16x8 __attribute__((ext_vector_type(8)));
typedef float floatx4 __attribute__((ext_vector_type(4)));

// ---------- fp32 -> bf16 weight conversion (qkv_w | proj_w | w1 | w2 contiguous) ----------
__global__ __launch_bounds__(256)
void cvt_all(const float* __restrict__ s0, const float* __restrict__ s1,
             const float* __restrict__ s2, const float* __restrict__ s3,
             bf16* __restrict__ dst) {
    int i = blockIdx.x * 256 + threadIdx.x;   // i < 442368 float4 chunks
    const int n0 = 110592, n1 = 36864, n2 = 147456;   // float4 counts
    const float4* src; int j;
    if (i < n0)           { src = (const float4*)s0; j = i; }
    else if (i < n0+n1)   { src = (const float4*)s1; j = i - n0; }
    else if (i < n0+n1+n2){ src = (const float4*)s2; j = i - n0 - n1; }
    else                  { src = (const float4*)s3; j = i - n0 - n1 - n2; }
    float4 v = src[j];
    bf16x4 o; o[0] = (bf16)v.x; o[1] = (bf16)v.y; o[2] = (bf16)v.z; o[3] = (bf16)v.w;
    ((bf16x4*)dst)[i] = o;
}

// ---------------- LayerNorm: one wave per token row (384 elems), fp32 in, bf16 out ----------
__global__ __launch_bounds__(64)
void ln_kernel(const float* __restrict__ x, const float* __restrict__ w,
               const float* __restrict__ b, bf16* __restrict__ out) {
    int row = blockIdx.x;
    int t = threadIdx.x;
    const float* xr = x + (size_t)row * DIMC;
    float vals[6];
    float s = 0.f;
    #pragma unroll
    for (int i = 0; i < 6; i++) { vals[i] = xr[t + i*64]; s += vals[i]; }
    #pragma unroll
    for (int m = 32; m; m >>= 1) s += __shfl_xor(s, m);
    float mean = s * (1.0f / DIMC);
    float sq = 0.f;
    #pragma unroll
    for (int i = 0; i < 6; i++) { float d = vals[i] - mean; sq += d * d; }
    #pragma unroll
    for (int m = 32; m; m >>= 1) sq += __shfl_xor(sq, m);
    float rstd = rsqrtf(sq * (1.0f / DIMC) + 1e-5f);
    bf16* orow = out + (size_t)row * DIMC;
    #pragma unroll
    for (int i = 0; i < 6; i++) {
        int c = t + i*64;
        orow[c] = (bf16)((vals[i] - mean) * rstd * w[c] + b[c]);
    }
}

// ---------------- GEMM: C[M,N] = A[M,K] @ W[N,K]^T, bf16 MFMA ----------------
// block = 4 waves (2x2), each wave 64x64 -> block tile 128x128.
// A-frag: A[row=lane&15][k=quad*8+j]; B-frag: W[col=lane&15][k=quad*8+j]
// C/D: col=lane&15, row=quad*4+reg  (verified layouts, m89/m91)
// EPI_QKV scatters q,k to [B,H,N,D] and v TRANSPOSED to [B,H,D,N] (packed 4-row stores).
enum { EPI_QKV = 1, EPI_RES = 2, EPI_GELU = 3 };

template<int EPI, typename OutT>
__global__ __launch_bounds__(256)
void gemm_bt(const bf16* __restrict__ A, const bf16* __restrict__ W,
             const float* __restrict__ bias, const float* res,
             OutT* out, int M, int N, int K) {
    int lane = threadIdx.x & 63;
    int w = threadIdx.x >> 6;
    int quad = lane >> 4, l16 = lane & 15;
    int rbase = blockIdx.y * 128 + (w >> 1) * 64;
    int cbase = blockIdx.x * 128 + (w & 1) * 64;
    floatx4 acc[4][4] = {};
    for (int k0 = 0; k0 < K; k0 += 32) {
        bf16x8 a[4], bf[4];
        #pragma unroll
        for (int tm = 0; tm < 4; tm++)
            a[tm] = *(const bf16x8*)(A + (size_t)(rbase + tm*16 + l16) * K + k0 + quad*8);
        #pragma unroll
        for (int tn = 0; tn < 4; tn++)
            bf[tn] = *(const bf16x8*)(W + (size_t)(cbase + tn*16 + l16) * K + k0 + quad*8);
        #pragma unroll
        for (int tm = 0; tm < 4; tm++)
            #pragma unroll
            for (int tn = 0; tn < 4; tn++)
                acc[tm][tn] = __builtin_amdgcn_mfma_f32_16x16x32_bf16(a[tm], bf[tn], acc[tm][tn], 0, 0, 0);
    }
    #pragma unroll
    for (int tm = 0; tm < 4; tm++)
        #pragma unroll
        for (int tn = 0; tn < 4; tn++) {
            if constexpr (EPI == EPI_QKV) {
                int colb = cbase + tn*16 + l16;       // uniform 'which' per tile (384%16==0)
                int which = colb / 384;
                int rowb = rbase + tm*16 + quad*4;
                int bb = rowb >> 10;
                if (which == 2) {
                    // V transposed: [B,H,D,N]; 4 consecutive n -> packed 8B store
                    int rem = colb - 768;
                    int hh = rem >> 6, d = rem & 63;
                    int n = rowb & 1023;
                    bf16x4 pk;
                    #pragma unroll
                    for (int r = 0; r < 4; r++) pk[r] = (bf16)acc[tm][tn][r];
                    *(bf16x4*)((bf16*)out + 2*TC + (((size_t)(bb*NH + hh) * HD + d) << 10) + n) = pk;
                } else {
                    int rem = colb - which*384;
                    int hh = rem >> 6, d = rem & 63;
                    #pragma unroll
                    for (int r = 0; r < 4; r++) {
                        int n = (rowb & 1023) + r;
                        ((bf16*)out)[(size_t)which*TC + (((size_t)(bb*NH + hh) * SEQ + n) << 6) + d]
                            = (bf16)acc[tm][tn][r];
                    }
                }
            } else {
                #pragma unroll
                for (int r = 0; r < 4; r++) {
                    int row = rbase + tm*16 + quad*4 + r;
                    int col = cbase + tn*16 + l16;
                    float v = acc[tm][tn][r];
                    v += bias[col];
                    if (EPI == EPI_RES)  v += res[(size_t)row * N + col];
                    if (EPI == EPI_GELU) v = 0.5f * v * (1.0f + erff(v * 0.70710678118f));
                    out[(size_t)row * N + col] = (OutT)v;
                }
            }
        }
}

// ---------------- Fused L2Q attention, split-K across 4 waves ----------------
// grid (SEQ/64, B*H); block = 256 (4 waves). Each block: 64 Q rows; wave w owns
// k-tiles [4w, 4w+4). K and V^T fragments load DIRECT from global (V pre-transposed
// by qkv epilogue). P round-trip through wave-private swizzled LDS (no loop barriers).
// rowsum via mfma(P, ones). Final cross-wave reduction through LDS (overlaid on P).
__global__ __launch_bounds__(256)
void attn_kernel(const bf16* __restrict__ q, const bf16* __restrict__ k,
                 const bf16* __restrict__ vt, const float* __restrict__ alpha,
                 const float* __restrict__ beta, const float* __restrict__ gamma,
                 bf16* __restrict__ attn_out) {
    __shared__ __align__(16) char smem[52992];
    bf16  (*Psh)[72] = (bf16(*)[72])smem;       // [4*64][72] wave-private P tiles
    float (*Ored)[68] = (float(*)[68])smem;     // [3*64][68] overlay (after loop)
    float* rsred = (float*)(smem + 52224);      // [3*64]

    int bh = blockIdx.y;
    int bb = bh / NH, h = bh % NH;
    int q0 = blockIdx.x * 64;
    int tid = threadIdx.x;
    int w = tid >> 6, lane = tid & 63, quad = lane >> 4, l16 = lane & 15;
    float av = alpha[h] * (QK_SCALE * QK_SCALE), bv = beta[h] * QK_SCALE, gv = gamma[h];
    const bf16* qb  = q  + (size_t)bh * SEQ * HD;
    const bf16* kb  = k  + (size_t)bh * SEQ * HD;
    const bf16* vtb = vt + (size_t)bh * HD * SEQ;

    bf16x8 qa[4][2];
    #pragma unroll
    for (int tm = 0; tm < 4; tm++)
        #pragma unroll
        for (int ks = 0; ks < 2; ks++)
            qa[tm][ks] = *(const bf16x8*)(qb + (size_t)(q0 + tm*16 + l16) * HD + ks*32 + quad*8);

    bf16x8 vone;
    #pragma unroll
    for (int j = 0; j < 8; j++) vone[j] = (bf16)1.0f;

    floatx4 o[4][4] = {};
    floatx4 rsacc[4] = {};
    int prow = w * 64;
    int rd_sw = ((l16 >> 2) & 3) << 3;

    for (int kt = w*4; kt < w*4 + 4; kt++) {
        int kb0 = kt * 64;
        bf16x8 kf[2][4];
        #pragma unroll
        for (int ks = 0; ks < 2; ks++)
            #pragma unroll
            for (int tn = 0; tn < 4; tn++)
                kf[ks][tn] = *(const bf16x8*)(kb + (size_t)(kb0 + tn*16 + l16) * HD + ks*32 + quad*8);
        #pragma unroll
        for (int tm = 0; tm < 4; tm++) {
            floatx4 s[4] = {};
            #pragma unroll
            for (int ks = 0; ks < 2; ks++)
                #pragma unroll
                for (int tn = 0; tn < 4; tn++)
                    s[tn] = __builtin_amdgcn_mfma_f32_16x16x32_bf16(qa[tm][ks], kf[ks][tn], s[tn], 0, 0, 0);
            #pragma unroll
            for (int tn = 0; tn < 4; tn++)
                #pragma unroll
                for (int r = 0; r < 4; r++) {
                    float xx = s[tn][r];
                    float p = fmaxf((av*xx + bv)*xx + gv, 0.f);
                    int row = tm*16 + quad*4 + r;
                    int col = (tn*16 + l16) ^ (quad << 3);   // bank swizzle
                    Psh[prow + row][col] = (bf16)p;
                }
        }
        #pragma unroll
        for (int ks = 0; ks < 2; ks++) {
            bf16x8 vf[4], pf[4];
            #pragma unroll
            for (int tn = 0; tn < 4; tn++)
                vf[tn] = *(const bf16x8*)(vtb + (size_t)(tn*16 + l16) * SEQ + kb0 + ks*32 + quad*8);
            #pragma unroll
            for (int tm = 0; tm < 4; tm++)
                pf[tm] = *(const bf16x8*)&Psh[prow + tm*16 + l16][(ks*32 + quad*8) ^ rd_sw];
            #pragma unroll
            for (int tm = 0; tm < 4; tm++)
                rsacc[tm] = __builtin_amdgcn_mfma_f32_16x16x32_bf16(pf[tm], vone, rsacc[tm], 0, 0, 0);
            #pragma unroll
            for (int tm = 0; tm < 4; tm++)
                #pragma unroll
                for (int tn = 0; tn < 4; tn++)
                    o[tm][tn] = __builtin_amdgcn_mfma_f32_16x16x32_bf16(pf[tm], vf[tn], o[tm][tn], 0, 0, 0);
        }
    }

    __syncthreads();                       // all P reads done -> safe to overlay
    if (w) {
        #pragma unroll
        for (int tm = 0; tm < 4; tm++) {
            #pragma unroll
            for (int tn = 0; tn < 4; tn++)
                #pragma unroll
                for (int r = 0; r < 4; r++)
                    Ored[(w-1)*64 + tm*16 + quad*4 + r][tn*16 + l16] = o[tm][tn][r];
            if (l16 == 0)
                #pragma unroll
                for (int r = 0; r < 4; r++)
                    rsred[(w-1)*64 + tm*16 + quad*4 + r] = rsacc[tm][r];
        }
    }
    __syncthreads();
    if (w == 0) {
        #pragma unroll
        for (int j = 0; j < 3; j++)
            #pragma unroll
            for (int tm = 0; tm < 4; tm++) {
                #pragma unroll
                for (int tn = 0; tn < 4; tn++)
                    #pragma unroll
                    for (int r = 0; r < 4; r++)
                        o[tm][tn][r] += Ored[j*64 + tm*16 + quad*4 + r][tn*16 + l16];
                #pragma unroll
                for (int r = 0; r < 4; r++)
                    rsacc[tm][r] += rsred[j*64 + tm*16 + quad*4 + r];
            }
        #pragma unroll
        for (int tm = 0; tm < 4; tm++)
            #pragma unroll
            for (int tn = 0; tn < 4; tn++)
                #pragma unroll
                for (int r = 0; r < 4; r++) {
                    int n = q0 + tm*16 + quad*4 + r;
                    attn_out[((size_t)(bb*SEQ + n)) * DIMC + h*HD + tn*16 + l16] =
                        (bf16)(o[tm][tn][r] / (rsacc[tm][r] + 1e-6f));
                }
    }
}

// ---------------- driver ----------------
extern "C" void kernel_launch(void* const* d_in, const int* in_sizes, int n_in,
                              void* d_out, int out_size, void* d_ws, size_t ws_size,
                              hipStream_t stream) {
    const float* x      = (const float*)d_in[0];
    const float* qkv_w  = (const float*)d_in[1];
    const float* proj_w = (const float*)d_in[2];
    const float* proj_b = (const float*)d_in[3];
    const float* alpha  = (const float*)d_in[4];
    const float* beta   = (const float*)d_in[5];
    const float* gamma  = (const float*)d_in[6];
    const float* ln1_w  = (const float*)d_in[7];
    const float* ln1_b  = (const float*)d_in[8];
    const float* ln2_w  = (const float*)d_in[9];
    const float* ln2_b  = (const float*)d_in[10];
    const float* w1     = (const float*)d_in[11];
    const float* b1     = (const float*)d_in[12];
    const float* w2     = (const float*)d_in[13];
    const float* b2     = (const float*)d_in[14];
    float* out = (float*)d_out;           // fp32 output; also doubles as x1 buffer

    // ws layout (bytes):
    //   [0, 3538944)            bf16 weights: qkv_w(442368) proj_w(147456) w1(589824) w2(589824)
    //   [3538944, 9830400)      h (TC bf16) — ln1 out, later ln2 out
    //   [9830400, 28704768)     qkv (3*TC bf16: q,k [B,H,N,D], v [B,H,D,N]) — overlaid by m later
    //   [28704768, 34996224)    attn_out (TC bf16) — tail of m overlay
    char* base = (char*)d_ws;
    bf16* wq_bf = (bf16*)base;                 // 1152x384
    bf16* wp_bf = wq_bf + 442368;              // 384x384
    bf16* w1_bf = wq_bf + 589824;              // 1536x384
    bf16* w2_bf = wq_bf + 1179648;             // 384x1536
    bf16* h        = (bf16*)(base + 3538944);
    bf16* qkv      = (bf16*)(base + 9830400);
    bf16* attn_o   = (bf16*)(base + 28704768);
    bf16* m        = qkv;                      // 4*TC, overlays qkv+attn_o (both dead by then)

    cvt_all<<<1728, 256, 0, stream>>>(qkv_w, proj_w, w1, w2, wq_bf);
    ln_kernel<<<T_TOK, 64, 0, stream>>>(x, ln1_w, ln1_b, h);
    gemm_bt<EPI_QKV, bf16><<<dim3(1152/128, T_TOK/128), 256, 0, stream>>>(
        h, wq_bf, nullptr, nullptr, qkv, T_TOK, 1152, DIMC);
    attn_kernel<<<dim3(SEQ/64, BS*NH), 256, 0, stream>>>(
        qkv, qkv + TC, qkv + 2*TC, alpha, beta, gamma, attn_o);
    gemm_bt<EPI_RES, float><<<dim3(DIMC/128, T_TOK/128), 256, 0, stream>>>(
        attn_o, wp_bf, proj_b, x, out /*x1*/, T_TOK, DIMC, DIMC);
    ln_kernel<<<T_TOK, 64, 0, stream>>>(out /*x1*/, ln2_w, ln2_b, h);
    gemm_bt<EPI_GELU, bf16><<<dim3(MLPD/128, T_TOK/128), 256, 0, stream>>>(
        h, w1_bf, b1, nullptr, m, T_TOK, MLPD, DIMC);
    gemm_bt<EPI_RES, float><<<dim3(DIMC/128, T_TOK/128), 256, 0, stream>>>(
        m, w2_bf, b2, out /*x1 (read-then-write in place, same element)*/, out, T_TOK, DIMC, MLPD);
}

// Round 4
// 244.393 us; speedup vs baseline: 1.3798x; 1.3398x over previous
//
#include <hip/hip_runtime.h>
#include <hip/hip_bf16.h>
#include <math.h>

#define DIMC 384
#define NH 6
#define HD 64
#define MLPD 1536
#define BS 8
#define SEQ 1024
#define T_TOK (BS*SEQ)                  // 8192 tokens
#define TC ((size_t)T_TOK*DIMC)         // 3,145,728 elems
#define QK_SCALE 0.125f                 // 64^-0.5

typedef __bf16 bf16;
typedef bf16 bf16x4 __attribute__((ext_vector_type(4)));
typedef bf16 bf16x8 __attribute__((ext_vector_type(8)));
typedef float floatx4 __attribute__((ext_vector_type(4)));

// async global->LDS 16B (per-lane LDS dest must equal wave-uniform-base + lane*16)
__device__ __forceinline__ void async_cp16(const void* gsrc, void* ldst) {
    __builtin_amdgcn_global_load_lds(
        (const __attribute__((address_space(1))) unsigned int*)gsrc,
        (__attribute__((address_space(3))) unsigned int*)ldst,
        16, 0, 0);
}

// ---------- fp32 -> bf16 weight conversion (qkv_w | proj_w | w1 | w2 contiguous) ----------
__global__ __launch_bounds__(256)
void cvt_all(const float* __restrict__ s0, const float* __restrict__ s1,
             const float* __restrict__ s2, const float* __restrict__ s3,
             bf16* __restrict__ dst) {
    int i = blockIdx.x * 256 + threadIdx.x;   // i < 442368 float4 chunks
    const int n0 = 110592, n1 = 36864, n2 = 147456;   // float4 counts
    const float4* src; int j;
    if (i < n0)           { src = (const float4*)s0; j = i; }
    else if (i < n0+n1)   { src = (const float4*)s1; j = i - n0; }
    else if (i < n0+n1+n2){ src = (const float4*)s2; j = i - n0 - n1; }
    else                  { src = (const float4*)s3; j = i - n0 - n1 - n2; }
    float4 v = src[j];
    bf16x4 o; o[0] = (bf16)v.x; o[1] = (bf16)v.y; o[2] = (bf16)v.z; o[3] = (bf16)v.w;
    ((bf16x4*)dst)[i] = o;
}

// ---------------- LayerNorm: 256 thr = 4 rows (1 wave/row), fp32 in, bf16 out ----------
__global__ __launch_bounds__(256)
void ln_kernel(const float* __restrict__ x, const float* __restrict__ w,
               const float* __restrict__ b, bf16* __restrict__ out) {
    int row = blockIdx.x * 4 + (threadIdx.x >> 6);
    int t = threadIdx.x & 63;
    const float* xr = x + (size_t)row * DIMC;
    float vals[6];
    float s = 0.f;
    #pragma unroll
    for (int i = 0; i < 6; i++) { vals[i] = xr[t + i*64]; s += vals[i]; }
    #pragma unroll
    for (int m = 32; m; m >>= 1) s += __shfl_xor(s, m);
    float mean = s * (1.0f / DIMC);
    float sq = 0.f;
    #pragma unroll
    for (int i = 0; i < 6; i++) { float d = vals[i] - mean; sq += d * d; }
    #pragma unroll
    for (int m = 32; m; m >>= 1) sq += __shfl_xor(sq, m);
    float rstd = rsqrtf(sq * (1.0f / DIMC) + 1e-5f);
    bf16* orow = out + (size_t)row * DIMC;
    #pragma unroll
    for (int i = 0; i < 6; i++) {
        int c = t + i*64;
        orow[c] = (bf16)((vals[i] - mean) * rstd * w[c] + b[c]);
    }
}

// ---- fused: x1 = x + Pp0 + Pp1 + proj_b (write fp32 x1) ; h = LN2(x1) (write bf16) ----
__global__ __launch_bounds__(256)
void ln2_fused(const float* __restrict__ x, const bf16* __restrict__ p0,
               const bf16* __restrict__ p1, const float* __restrict__ pb,
               const float* __restrict__ w, const float* __restrict__ b,
               float* __restrict__ x1, bf16* __restrict__ h) {
    int row = blockIdx.x * 4 + (threadIdx.x >> 6);
    int t = threadIdx.x & 63;
    size_t base = (size_t)row * DIMC;
    float vals[6];
    float s = 0.f;
    #pragma unroll
    for (int i = 0; i < 6; i++) {
        int c = t + i*64;
        float v = x[base + c] + (float)p0[base + c] + (float)p1[base + c] + pb[c];
        vals[i] = v; s += v;
    }
    #pragma unroll
    for (int m = 32; m; m >>= 1) s += __shfl_xor(s, m);
    float mean = s * (1.0f / DIMC);
    float sq = 0.f;
    #pragma unroll
    for (int i = 0; i < 6; i++) { float d = vals[i] - mean; sq += d * d; }
    #pragma unroll
    for (int m = 32; m; m >>= 1) sq += __shfl_xor(sq, m);
    float rstd = rsqrtf(sq * (1.0f / DIMC) + 1e-5f);
    #pragma unroll
    for (int i = 0; i < 6; i++) {
        int c = t + i*64;
        x1[base + c] = vals[i];
        h[base + c] = (bf16)((vals[i] - mean) * rstd * w[c] + b[c]);
    }
}

// ---- final: out = x1 + b2 + Pm0+Pm1+Pm2+Pm3 (bf16 partials), float4-vectorized ----
__global__ __launch_bounds__(256)
void reduce4(float* __restrict__ xo, const bf16* __restrict__ p0, const bf16* __restrict__ p1,
             const bf16* __restrict__ p2, const bf16* __restrict__ p3,
             const float* __restrict__ b2) {
    int i = blockIdx.x * 256 + threadIdx.x;   // float4 index, < TC/4
    float4 v = ((const float4*)xo)[i];
    int c = (i % 96) * 4;
    float4 bb = *(const float4*)(b2 + c);
    bf16x4 a0 = ((const bf16x4*)p0)[i], a1 = ((const bf16x4*)p1)[i];
    bf16x4 a2 = ((const bf16x4*)p2)[i], a3 = ((const bf16x4*)p3)[i];
    v.x += bb.x + (float)a0[0] + (float)a1[0] + (float)a2[0] + (float)a3[0];
    v.y += bb.y + (float)a0[1] + (float)a1[1] + (float)a2[1] + (float)a3[1];
    v.z += bb.z + (float)a0[2] + (float)a1[2] + (float)a2[2] + (float)a3[2];
    v.w += bb.w + (float)a0[3] + (float)a1[3] + (float)a2[3] + (float)a3[3];
    ((float4*)xo)[i] = v;
}

// ---------------- GEMM: C[M,N] = A[M,K] @ W[N,K]^T, m97-style LDS staging ----------------
// block = 4 waves (2x2), tile 128x128, BK=32, global_load_lds width-16 into packed
// [128][32] bf16 LDS (no padding -- required by lds-DMA lane mapping). K compile-time,
// KS-way split-K along grid.z (EPI_NONE writes bf16 partials at out + z*M*N).
enum { EPI_NONE = 0, EPI_QKV = 1, EPI_GELU = 3 };

template<int EPI, int K, int KS, typename OutT>
__global__ __launch_bounds__(256)
void gemm_bt(const bf16* __restrict__ A, const bf16* __restrict__ W,
             const float* __restrict__ bias, OutT* out, int M, int N) {
    __shared__ __align__(16) bf16 Ash[128*32];
    __shared__ __align__(16) bf16 Bsh[128*32];
    constexpr int KB = K / KS;               // K extent per block
    int tid = threadIdx.x;
    int lane = tid & 63, w = tid >> 6;
    int quad = lane >> 4, l16 = lane & 15;
    int rbase = blockIdx.y * 128 + (w >> 1) * 64;
    int cbase = blockIdx.x * 128 + (w & 1) * 64;
    int kbase = blockIdx.z * KB;
    // staging chunk ids: 512 x 16B per tile; each thread stages 2 A + 2 B chunks
    int c1 = w * 64 + lane;                  // [0,256)
    int c2 = c1 + 256;                       // [256,512)
    const bf16* Ag1 = A + (size_t)(blockIdx.y*128 + (c1 >> 2)) * K + kbase + (c1 & 3) * 8;
    const bf16* Ag2 = A + (size_t)(blockIdx.y*128 + (c2 >> 2)) * K + kbase + (c2 & 3) * 8;
    const bf16* Wg1 = W + (size_t)(blockIdx.x*128 + (c1 >> 2)) * K + kbase + (c1 & 3) * 8;
    const bf16* Wg2 = W + (size_t)(blockIdx.x*128 + (c2 >> 2)) * K + kbase + (c2 & 3) * 8;
    bf16* As1 = Ash + c1 * 8;  bf16* As2 = Ash + c2 * 8;
    bf16* Bs1 = Bsh + c1 * 8;  bf16* Bs2 = Bsh + c2 * 8;

    int arow = (w >> 1) * 64;                // wave's row offset within tile
    int brow = (w & 1) * 64;
    floatx4 acc[4][4] = {};
    #pragma unroll
    for (int kk = 0; kk < KB / 32; kk++) {
        __syncthreads();                     // prev iter's LDS reads complete
        async_cp16(Ag1 + kk*32, As1);
        async_cp16(Ag2 + kk*32, As2);
        async_cp16(Wg1 + kk*32, Bs1);
        async_cp16(Wg2 + kk*32, Bs2);
        __syncthreads();                     // drains vmcnt (lds-DMA) + lgkmcnt
        bf16x8 a[4], bfr[4];
        #pragma unroll
        for (int tm = 0; tm < 4; tm++)
            a[tm] = *(const bf16x8*)&Ash[(arow + tm*16 + l16) * 32 + quad*8];
        #pragma unroll
        for (int tn = 0; tn < 4; tn++)
            bfr[tn] = *(const bf16x8*)&Bsh[(brow + tn*16 + l16) * 32 + quad*8];
        #pragma unroll
        for (int tm = 0; tm < 4; tm++)
            #pragma unroll
            for (int tn = 0; tn < 4; tn++)
                acc[tm][tn] = __builtin_amdgcn_mfma_f32_16x16x32_bf16(a[tm], bfr[tn], acc[tm][tn], 0, 0, 0);
    }

    #pragma unroll
    for (int tm = 0; tm < 4; tm++)
        #pragma unroll
        for (int tn = 0; tn < 4; tn++) {
            if constexpr (EPI == EPI_QKV) {
                int colb = cbase + tn*16 + l16;       // uniform 'which' per tile (384%16==0)
                int which = colb / 384;
                int rowb = rbase + tm*16 + quad*4;
                int bb = rowb >> 10;
                if (which == 2) {
                    // V transposed: [B,H,D,N]; 4 consecutive n -> packed 8B store
                    int rem = colb - 768;
                    int hh = rem >> 6, d = rem & 63;
                    int n = rowb & 1023;
                    bf16x4 pk;
                    #pragma unroll
                    for (int r = 0; r < 4; r++) pk[r] = (bf16)acc[tm][tn][r];
                    *(bf16x4*)((bf16*)out + 2*TC + (((size_t)(bb*NH + hh) * HD + d) << 10) + n) = pk;
                } else {
                    int rem = colb - which*384;
                    int hh = rem >> 6, d = rem & 63;
                    #pragma unroll
                    for (int r = 0; r < 4; r++) {
                        int n = (rowb & 1023) + r;
                        ((bf16*)out)[(size_t)which*TC + (((size_t)(bb*NH + hh) * SEQ + n) << 6) + d]
                            = (bf16)acc[tm][tn][r];
                    }
                }
            } else if constexpr (EPI == EPI_NONE) {
                OutT* ob = out + (size_t)blockIdx.z * M * N;
                #pragma unroll
                for (int r = 0; r < 4; r++) {
                    int row = rbase + tm*16 + quad*4 + r;
                    int col = cbase + tn*16 + l16;
                    ob[(size_t)row * N + col] = (OutT)acc[tm][tn][r];
                }
            } else {  // EPI_GELU
                #pragma unroll
                for (int r = 0; r < 4; r++) {
                    int row = rbase + tm*16 + quad*4 + r;
                    int col = cbase + tn*16 + l16;
                    float v = acc[tm][tn][r] + bias[col];
                    v = 0.5f * v * (1.0f + erff(v * 0.70710678118f));
                    out[(size_t)row * N + col] = (OutT)v;
                }
            }
        }
}

// ---------------- Fused L2Q attention, split-K across 4 waves (round-3, unchanged) -------
__global__ __launch_bounds__(256)
void attn_kernel(const bf16* __restrict__ q, const bf16* __restrict__ k,
                 const bf16* __restrict__ vt, const float* __restrict__ alpha,
                 const float* __restrict__ beta, const float* __restrict__ gamma,
                 bf16* __restrict__ attn_out) {
    __shared__ __align__(16) char smem[52992];
    bf16  (*Psh)[72] = (bf16(*)[72])smem;       // [4*64][72] wave-private P tiles
    float (*Ored)[68] = (float(*)[68])smem;     // [3*64][68] overlay (after loop)
    float* rsred = (float*)(smem + 52224);      // [3*64]

    int bh = blockIdx.y;
    int bb = bh / NH, h = bh % NH;
    int q0 = blockIdx.x * 64;
    int tid = threadIdx.x;
    int w = tid >> 6, lane = tid & 63, quad = lane >> 4, l16 = lane & 15;
    float av = alpha[h] * (QK_SCALE * QK_SCALE), bv = beta[h] * QK_SCALE, gv = gamma[h];
    const bf16* qb  = q  + (size_t)bh * SEQ * HD;
    const bf16* kb  = k  + (size_t)bh * SEQ * HD;
    const bf16* vtb = vt + (size_t)bh * HD * SEQ;

    bf16x8 qa[4][2];
    #pragma unroll
    for (int tm = 0; tm < 4; tm++)
        #pragma unroll
        for (int ks = 0; ks < 2; ks++)
            qa[tm][ks] = *(const bf16x8*)(qb + (size_t)(q0 + tm*16 + l16) * HD + ks*32 + quad*8);

    bf16x8 vone;
    #pragma unroll
    for (int j = 0; j < 8; j++) vone[j] = (bf16)1.0f;

    floatx4 o[4][4] = {};
    floatx4 rsacc[4] = {};
    int prow = w * 64;
    int rd_sw = ((l16 >> 2) & 3) << 3;

    for (int kt = w*4; kt < w*4 + 4; kt++) {
        int kb0 = kt * 64;
        bf16x8 kf[2][4];
        #pragma unroll
        for (int ks = 0; ks < 2; ks++)
            #pragma unroll
            for (int tn = 0; tn < 4; tn++)
                kf[ks][tn] = *(const bf16x8*)(kb + (size_t)(kb0 + tn*16 + l16) * HD + ks*32 + quad*8);
        #pragma unroll
        for (int tm = 0; tm < 4; tm++) {
            floatx4 s[4] = {};
            #pragma unroll
            for (int ks = 0; ks < 2; ks++)
                #pragma unroll
                for (int tn = 0; tn < 4; tn++)
                    s[tn] = __builtin_amdgcn_mfma_f32_16x16x32_bf16(qa[tm][ks], kf[ks][tn], s[tn], 0, 0, 0);
            #pragma unroll
            for (int tn = 0; tn < 4; tn++)
                #pragma unroll
                for (int r = 0; r < 4; r++) {
                    float xx = s[tn][r];
                    float p = fmaxf((av*xx + bv)*xx + gv, 0.f);
                    int row = tm*16 + quad*4 + r;
                    int col = (tn*16 + l16) ^ (quad << 3);   // bank swizzle
                    Psh[prow + row][col] = (bf16)p;
                }
        }
        #pragma unroll
        for (int ks = 0; ks < 2; ks++) {
            bf16x8 vf[4], pf[4];
            #pragma unroll
            for (int tn = 0; tn < 4; tn++)
                vf[tn] = *(const bf16x8*)(vtb + (size_t)(tn*16 + l16) * SEQ + kb0 + ks*32 + quad*8);
            #pragma unroll
            for (int tm = 0; tm < 4; tm++)
                pf[tm] = *(const bf16x8*)&Psh[prow + tm*16 + l16][(ks*32 + quad*8) ^ rd_sw];
            #pragma unroll
            for (int tm = 0; tm < 4; tm++)
                rsacc[tm] = __builtin_amdgcn_mfma_f32_16x16x32_bf16(pf[tm], vone, rsacc[tm], 0, 0, 0);
            #pragma unroll
            for (int tm = 0; tm < 4; tm++)
                #pragma unroll
                for (int tn = 0; tn < 4; tn++)
                    o[tm][tn] = __builtin_amdgcn_mfma_f32_16x16x32_bf16(pf[tm], vf[tn], o[tm][tn], 0, 0, 0);
        }
    }

    __syncthreads();                       // all P reads done -> safe to overlay
    if (w) {
        #pragma unroll
        for (int tm = 0; tm < 4; tm++) {
            #pragma unroll
            for (int tn = 0; tn < 4; tn++)
                #pragma unroll
                for (int r = 0; r < 4; r++)
                    Ored[(w-1)*64 + tm*16 + quad*4 + r][tn*16 + l16] = o[tm][tn][r];
            if (l16 == 0)
                #pragma unroll
                for (int r = 0; r < 4; r++)
                    rsred[(w-1)*64 + tm*16 + quad*4 + r] = rsacc[tm][r];
        }
    }
    __syncthreads();
    if (w == 0) {
        #pragma unroll
        for (int j = 0; j < 3; j++)
            #pragma unroll
            for (int tm = 0; tm < 4; tm++) {
                #pragma unroll
                for (int tn = 0; tn < 4; tn++)
                    #pragma unroll
                    for (int r = 0; r < 4; r++)
                        o[tm][tn][r] += Ored[j*64 + tm*16 + quad*4 + r][tn*16 + l16];
                #pragma unroll
                for (int r = 0; r < 4; r++)
                    rsacc[tm][r] += rsred[j*64 + tm*16 + quad*4 + r];
            }
        #pragma unroll
        for (int tm = 0; tm < 4; tm++)
            #pragma unroll
            for (int tn = 0; tn < 4; tn++)
                #pragma unroll
                for (int r = 0; r < 4; r++) {
                    int n = q0 + tm*16 + quad*4 + r;
                    attn_out[((size_t)(bb*SEQ + n)) * DIMC + h*HD + tn*16 + l16] =
                        (bf16)(o[tm][tn][r] / (rsacc[tm][r] + 1e-6f));
                }
    }
}

// ---------------- driver ----------------
extern "C" void kernel_launch(void* const* d_in, const int* in_sizes, int n_in,
                              void* d_out, int out_size, void* d_ws, size_t ws_size,
                              hipStream_t stream) {
    const float* x      = (const float*)d_in[0];
    const float* qkv_w  = (const float*)d_in[1];
    const float* proj_w = (const float*)d_in[2];
    const float* proj_b = (const float*)d_in[3];
    const float* alpha  = (const float*)d_in[4];
    const float* beta   = (const float*)d_in[5];
    const float* gamma  = (const float*)d_in[6];
    const float* ln1_w  = (const float*)d_in[7];
    const float* ln1_b  = (const float*)d_in[8];
    const float* ln2_w  = (const float*)d_in[9];
    const float* ln2_b  = (const float*)d_in[10];
    const float* w1     = (const float*)d_in[11];
    const float* b1     = (const float*)d_in[12];
    const float* w2     = (const float*)d_in[13];
    const float* b2     = (const float*)d_in[14];
    float* out = (float*)d_out;           // fp32 output; also doubles as x1 buffer

    // ws layout (bytes):
    //   [0, 3538944)             bf16 weights: qkv_w(442368) proj_w(147456) w1(589824) w2(589824)
    //   [3538944, 9830400)       h (TC bf16) — ln1 out, later ln2 out
    //   [9830400, 28704768)      qkv (3*TC bf16: q,k [B,H,N,D], v [B,H,D,N])
    //   [28704768, 34996224)     attn_o (TC bf16)
    //   m (4*TC bf16) overlays [9830400, 34996224) once qkv+attn_o are dead
    //   [34996224, 60162048)     Pm: mlp2 partials (4*TC bf16); Pp (2*TC bf16) overlays its head
    char* base = (char*)d_ws;
    bf16* wq_bf = (bf16*)base;                 // 1152x384
    bf16* wp_bf = wq_bf + 442368;              // 384x384
    bf16* w1_bf = wq_bf + 589824;              // 1536x384
    bf16* w2_bf = wq_bf + 1179648;             // 384x1536
    bf16* h      = (bf16*)(base + 3538944);
    bf16* qkv    = (bf16*)(base + 9830400);
    bf16* attn_o = (bf16*)(base + 28704768);
    bf16* m      = qkv;                        // overlays qkv+attn_o (both dead by mlp1)
    bf16* Pp     = (bf16*)(base + 34996224);   // 2*TC (proj split-K partials)
    bf16* Pm     = (bf16*)(base + 34996224);   // 4*TC (mlp2 split-K partials; Pp dead)

    cvt_all<<<1728, 256, 0, stream>>>(qkv_w, proj_w, w1, w2, wq_bf);
    ln_kernel<<<T_TOK/4, 256, 0, stream>>>(x, ln1_w, ln1_b, h);
    gemm_bt<EPI_QKV, 384, 1, bf16><<<dim3(9, 64, 1), 256, 0, stream>>>(
        h, wq_bf, nullptr, qkv, T_TOK, 1152);
    attn_kernel<<<dim3(SEQ/64, BS*NH), 256, 0, stream>>>(
        qkv, qkv + TC, qkv + 2*TC, alpha, beta, gamma, attn_o);
    gemm_bt<EPI_NONE, 384, 2, bf16><<<dim3(3, 64, 2), 256, 0, stream>>>(
        attn_o, wp_bf, nullptr, Pp, T_TOK, DIMC);
    ln2_fused<<<T_TOK/4, 256, 0, stream>>>(x, Pp, Pp + TC, proj_b, ln2_w, ln2_b, out, h);
    gemm_bt<EPI_GELU, 384, 1, bf16><<<dim3(12, 64, 1), 256, 0, stream>>>(
        h, w1_bf, b1, m, T_TOK, MLPD);
    gemm_bt<EPI_NONE, 1536, 4, bf16><<<dim3(3, 64, 4), 256, 0, stream>>>(
        m, w2_bf, nullptr, Pm, T_TOK, DIMC);
    reduce4<<<TC/4/256, 256, 0, stream>>>(out, Pm, Pm + TC, Pm + 2*TC, Pm + 3*TC, b2);
}

// Round 5
// 243.298 us; speedup vs baseline: 1.3860x; 1.0045x over previous
//
#include <hip/hip_runtime.h>
#include <hip/hip_bf16.h>
#include <math.h>

#define DIMC 384
#define NH 6
#define HD 64
#define MLPD 1536
#define BS 8
#define SEQ 1024
#define T_TOK (BS*SEQ)                  // 8192 tokens
#define TC ((size_t)T_TOK*DIMC)         // 3,145,728 elems
#define QK_SCALE 0.125f                 // 64^-0.5

typedef __bf16 bf16;
typedef bf16 bf16x4 __attribute__((ext_vector_type(4)));
typedef bf16 bf16x8 __attribute__((ext_vector_type(8)));
typedef float floatx4 __attribute__((ext_vector_type(4)));

// async global->LDS 16B (per-lane LDS dest must equal wave-uniform-base + lane*16)
__device__ __forceinline__ void async_cp16(const void* gsrc, void* ldst) {
    __builtin_amdgcn_global_load_lds(
        (const __attribute__((address_space(1))) unsigned int*)gsrc,
        (__attribute__((address_space(3))) unsigned int*)ldst,
        16, 0, 0);
}

// ---------- fp32 -> bf16 weight conversion (qkv_w | proj_w | w1 | w2 contiguous) ----------
__global__ __launch_bounds__(256)
void cvt_all(const float* __restrict__ s0, const float* __restrict__ s1,
             const float* __restrict__ s2, const float* __restrict__ s3,
             bf16* __restrict__ dst) {
    int i = blockIdx.x * 256 + threadIdx.x;   // i < 442368 float4 chunks
    const int n0 = 110592, n1 = 36864, n2 = 147456;   // float4 counts
    const float4* src; int j;
    if (i < n0)           { src = (const float4*)s0; j = i; }
    else if (i < n0+n1)   { src = (const float4*)s1; j = i - n0; }
    else if (i < n0+n1+n2){ src = (const float4*)s2; j = i - n0 - n1; }
    else                  { src = (const float4*)s3; j = i - n0 - n1 - n2; }
    float4 v = src[j];
    bf16x4 o; o[0] = (bf16)v.x; o[1] = (bf16)v.y; o[2] = (bf16)v.z; o[3] = (bf16)v.w;
    ((bf16x4*)dst)[i] = o;
}

// ---------------- LayerNorm: 256 thr = 4 rows (1 wave/row), fp32 in, bf16 out ----------
__global__ __launch_bounds__(256)
void ln_kernel(const float* __restrict__ x, const float* __restrict__ w,
               const float* __restrict__ b, bf16* __restrict__ out) {
    int row = blockIdx.x * 4 + (threadIdx.x >> 6);
    int t = threadIdx.x & 63;
    const float* xr = x + (size_t)row * DIMC;
    float vals[6];
    float s = 0.f;
    #pragma unroll
    for (int i = 0; i < 6; i++) { vals[i] = xr[t + i*64]; s += vals[i]; }
    #pragma unroll
    for (int m = 32; m; m >>= 1) s += __shfl_xor(s, m);
    float mean = s * (1.0f / DIMC);
    float sq = 0.f;
    #pragma unroll
    for (int i = 0; i < 6; i++) { float d = vals[i] - mean; sq += d * d; }
    #pragma unroll
    for (int m = 32; m; m >>= 1) sq += __shfl_xor(sq, m);
    float rstd = rsqrtf(sq * (1.0f / DIMC) + 1e-5f);
    bf16* orow = out + (size_t)row * DIMC;
    #pragma unroll
    for (int i = 0; i < 6; i++) {
        int c = t + i*64;
        orow[c] = (bf16)((vals[i] - mean) * rstd * w[c] + b[c]);
    }
}

// ---- fused: x1 = x + Pp0 + Pp1 + proj_b (write fp32 x1) ; h = LN2(x1) (write bf16) ----
__global__ __launch_bounds__(256)
void ln2_fused(const float* __restrict__ x, const bf16* __restrict__ p0,
               const bf16* __restrict__ p1, const float* __restrict__ pb,
               const float* __restrict__ w, const float* __restrict__ b,
               float* __restrict__ x1, bf16* __restrict__ h) {
    int row = blockIdx.x * 4 + (threadIdx.x >> 6);
    int t = threadIdx.x & 63;
    size_t base = (size_t)row * DIMC;
    float vals[6];
    float s = 0.f;
    #pragma unroll
    for (int i = 0; i < 6; i++) {
        int c = t + i*64;
        float v = x[base + c] + (float)p0[base + c] + (float)p1[base + c] + pb[c];
        vals[i] = v; s += v;
    }
    #pragma unroll
    for (int m = 32; m; m >>= 1) s += __shfl_xor(s, m);
    float mean = s * (1.0f / DIMC);
    float sq = 0.f;
    #pragma unroll
    for (int i = 0; i < 6; i++) { float d = vals[i] - mean; sq += d * d; }
    #pragma unroll
    for (int m = 32; m; m >>= 1) sq += __shfl_xor(sq, m);
    float rstd = rsqrtf(sq * (1.0f / DIMC) + 1e-5f);
    #pragma unroll
    for (int i = 0; i < 6; i++) {
        int c = t + i*64;
        x1[base + c] = vals[i];
        h[base + c] = (bf16)((vals[i] - mean) * rstd * w[c] + b[c]);
    }
}

// ---- final: out = x1 + b2 + Pm0+Pm1+Pm2+Pm3 (bf16 partials), float4-vectorized ----
__global__ __launch_bounds__(256)
void reduce4(float* __restrict__ xo, const bf16* __restrict__ p0, const bf16* __restrict__ p1,
             const bf16* __restrict__ p2, const bf16* __restrict__ p3,
             const float* __restrict__ b2) {
    int i = blockIdx.x * 256 + threadIdx.x;   // float4 index, < TC/4
    float4 v = ((const float4*)xo)[i];
    int c = (i % 96) * 4;
    float4 bb = *(const float4*)(b2 + c);
    bf16x4 a0 = ((const bf16x4*)p0)[i], a1 = ((const bf16x4*)p1)[i];
    bf16x4 a2 = ((const bf16x4*)p2)[i], a3 = ((const bf16x4*)p3)[i];
    v.x += bb.x + (float)a0[0] + (float)a1[0] + (float)a2[0] + (float)a3[0];
    v.y += bb.y + (float)a0[1] + (float)a1[1] + (float)a2[1] + (float)a3[1];
    v.z += bb.z + (float)a0[2] + (float)a1[2] + (float)a2[2] + (float)a3[2];
    v.w += bb.w + (float)a0[3] + (float)a1[3] + (float)a2[3] + (float)a3[3];
    ((float4*)xo)[i] = v;
}

// ---------------- GEMM: C[M,N] = A[M,K] @ W[N,K]^T, m97-style LDS staging ----------------
// block = 4 waves (2x2), tile 128x128, BK=32, global_load_lds width-16 into packed
// [128][32] bf16 LDS (no padding -- required by lds-DMA lane mapping). K compile-time,
// KS-way split-K along grid.z (EPI_NONE writes bf16 partials at out + z*M*N).
enum { EPI_NONE = 0, EPI_QKV = 1, EPI_GELU = 3 };

template<int EPI, int K, int KS, typename OutT>
__global__ __launch_bounds__(256)
void gemm_bt(const bf16* __restrict__ A, const bf16* __restrict__ W,
             const float* __restrict__ bias, OutT* out, int M, int N) {
    __shared__ __align__(16) bf16 Ash[128*32];
    __shared__ __align__(16) bf16 Bsh[128*32];
    constexpr int KB = K / KS;               // K extent per block
    int tid = threadIdx.x;
    int lane = tid & 63, w = tid >> 6;
    int quad = lane >> 4, l16 = lane & 15;
    int rbase = blockIdx.y * 128 + (w >> 1) * 64;
    int cbase = blockIdx.x * 128 + (w & 1) * 64;
    int kbase = blockIdx.z * KB;
    // staging chunk ids: 512 x 16B per tile; each thread stages 2 A + 2 B chunks
    int c1 = w * 64 + lane;                  // [0,256)
    int c2 = c1 + 256;                       // [256,512)
    const bf16* Ag1 = A + (size_t)(blockIdx.y*128 + (c1 >> 2)) * K + kbase + (c1 & 3) * 8;
    const bf16* Ag2 = A + (size_t)(blockIdx.y*128 + (c2 >> 2)) * K + kbase + (c2 & 3) * 8;
    const bf16* Wg1 = W + (size_t)(blockIdx.x*128 + (c1 >> 2)) * K + kbase + (c1 & 3) * 8;
    const bf16* Wg2 = W + (size_t)(blockIdx.x*128 + (c2 >> 2)) * K + kbase + (c2 & 3) * 8;
    bf16* As1 = Ash + c1 * 8;  bf16* As2 = Ash + c2 * 8;
    bf16* Bs1 = Bsh + c1 * 8;  bf16* Bs2 = Bsh + c2 * 8;

    int arow = (w >> 1) * 64;                // wave's row offset within tile
    int brow = (w & 1) * 64;
    floatx4 acc[4][4] = {};
    #pragma unroll
    for (int kk = 0; kk < KB / 32; kk++) {
        __syncthreads();                     // prev iter's LDS reads complete
        async_cp16(Ag1 + kk*32, As1);
        async_cp16(Ag2 + kk*32, As2);
        async_cp16(Wg1 + kk*32, Bs1);
        async_cp16(Wg2 + kk*32, Bs2);
        __syncthreads();                     // drains vmcnt (lds-DMA) + lgkmcnt
        bf16x8 a[4], bfr[4];
        #pragma unroll
        for (int tm = 0; tm < 4; tm++)
            a[tm] = *(const bf16x8*)&Ash[(arow + tm*16 + l16) * 32 + quad*8];
        #pragma unroll
        for (int tn = 0; tn < 4; tn++)
            bfr[tn] = *(const bf16x8*)&Bsh[(brow + tn*16 + l16) * 32 + quad*8];
        #pragma unroll
        for (int tm = 0; tm < 4; tm++)
            #pragma unroll
            for (int tn = 0; tn < 4; tn++)
                acc[tm][tn] = __builtin_amdgcn_mfma_f32_16x16x32_bf16(a[tm], bfr[tn], acc[tm][tn], 0, 0, 0);
    }

    #pragma unroll
    for (int tm = 0; tm < 4; tm++)
        #pragma unroll
        for (int tn = 0; tn < 4; tn++) {
            if constexpr (EPI == EPI_QKV) {
                int colb = cbase + tn*16 + l16;       // uniform 'which' per tile (384%16==0)
                int which = colb / 384;
                int rowb = rbase + tm*16 + quad*4;
                int bb = rowb >> 10;
                if (which == 2) {
                    // V transposed: [B,H,D,N]; 4 consecutive n -> packed 8B store
                    int rem = colb - 768;
                    int hh = rem >> 6, d = rem & 63;
                    int n = rowb & 1023;
                    bf16x4 pk;
                    #pragma unroll
                    for (int r = 0; r < 4; r++) pk[r] = (bf16)acc[tm][tn][r];
                    *(bf16x4*)((bf16*)out + 2*TC + (((size_t)(bb*NH + hh) * HD + d) << 10) + n) = pk;
                } else {
                    int rem = colb - which*384;
                    int hh = rem >> 6, d = rem & 63;
                    #pragma unroll
                    for (int r = 0; r < 4; r++) {
                        int n = (rowb & 1023) + r;
                        ((bf16*)out)[(size_t)which*TC + (((size_t)(bb*NH + hh) * SEQ + n) << 6) + d]
                            = (bf16)acc[tm][tn][r];
                    }
                }
            } else if constexpr (EPI == EPI_NONE) {
                OutT* ob = out + (size_t)blockIdx.z * M * N;
                #pragma unroll
                for (int r = 0; r < 4; r++) {
                    int row = rbase + tm*16 + quad*4 + r;
                    int col = cbase + tn*16 + l16;
                    ob[(size_t)row * N + col] = (OutT)acc[tm][tn][r];
                }
            } else {  // EPI_GELU
                #pragma unroll
                for (int r = 0; r < 4; r++) {
                    int row = rbase + tm*16 + quad*4 + r;
                    int col = cbase + tn*16 + l16;
                    float v = acc[tm][tn][r] + bias[col];
                    v = 0.5f * v * (1.0f + erff(v * 0.70710678118f));
                    out[(size_t)row * N + col] = (OutT)v;
                }
            }
        }
}

// ---------------- Fused L2Q attention, split-K across 4 waves ----------------
// 1-D grid of 768 blocks with XCD-aware decode: xcd = L&7 (round-robin dispatch),
// all 16 q-tiles of a head land on the same XCD -> per-XCD K/V working set
// 6 heads x 256 KB = 1.5 MB < 4 MB L2 (was 48 heads x 256 KB = 12.3 MB -> thrash).
__global__ __launch_bounds__(256)
void attn_kernel(const bf16* __restrict__ q, const bf16* __restrict__ k,
                 const bf16* __restrict__ vt, const float* __restrict__ alpha,
                 const float* __restrict__ beta, const float* __restrict__ gamma,
                 bf16* __restrict__ attn_out) {
    __shared__ __align__(16) char smem[52992];
    bf16  (*Psh)[72] = (bf16(*)[72])smem;       // [4*64][72] wave-private P tiles
    float (*Ored)[68] = (float(*)[68])smem;     // [3*64][68] overlay (after loop)
    float* rsred = (float*)(smem + 52224);      // [3*64]

    int L = blockIdx.x;
    int xcd = L & 7, slot = L >> 3;
    int qt = slot & 15;
    int bh = xcd + ((slot >> 4) << 3);          // {xcd, xcd+8, ..., xcd+40}
    int bb = bh / NH, h = bh % NH;
    int q0 = qt * 64;
    int tid = threadIdx.x;
    int w = tid >> 6, lane = tid & 63, quad = lane >> 4, l16 = lane & 15;
    float av = alpha[h] * (QK_SCALE * QK_SCALE), bv = beta[h] * QK_SCALE, gv = gamma[h];
    const bf16* qb  = q  + (size_t)bh * SEQ * HD;
    const bf16* kb  = k  + (size_t)bh * SEQ * HD;
    const bf16* vtb = vt + (size_t)bh * HD * SEQ;

    bf16x8 qa[4][2];
    #pragma unroll
    for (int tm = 0; tm < 4; tm++)
        #pragma unroll
        for (int ks = 0; ks < 2; ks++)
            qa[tm][ks] = *(const bf16x8*)(qb + (size_t)(q0 + tm*16 + l16) * HD + ks*32 + quad*8);

    bf16x8 vone;
    #pragma unroll
    for (int j = 0; j < 8; j++) vone[j] = (bf16)1.0f;

    floatx4 o[4][4] = {};
    floatx4 rsacc[4] = {};
    int prow = w * 64;
    int rd_sw = ((l16 >> 2) & 3) << 3;

    for (int kt = w*4; kt < w*4 + 4; kt++) {
        int kb0 = kt * 64;
        bf16x8 kf[2][4];
        #pragma unroll
        for (int ks = 0; ks < 2; ks++)
            #pragma unroll
            for (int tn = 0; tn < 4; tn++)
                kf[ks][tn] = *(const bf16x8*)(kb + (size_t)(kb0 + tn*16 + l16) * HD + ks*32 + quad*8);
        #pragma unroll
        for (int tm = 0; tm < 4; tm++) {
            floatx4 s[4] = {};
            #pragma unroll
            for (int ks = 0; ks < 2; ks++)
                #pragma unroll
                for (int tn = 0; tn < 4; tn++)
                    s[tn] = __builtin_amdgcn_mfma_f32_16x16x32_bf16(qa[tm][ks], kf[ks][tn], s[tn], 0, 0, 0);
            #pragma unroll
            for (int tn = 0; tn < 4; tn++)
                #pragma unroll
                for (int r = 0; r < 4; r++) {
                    float xx = s[tn][r];
                    float p = fmaxf((av*xx + bv)*xx + gv, 0.f);
                    int row = tm*16 + quad*4 + r;
                    int col = (tn*16 + l16) ^ (quad << 3);   // bank swizzle
                    Psh[prow + row][col] = (bf16)p;
                }
        }
        #pragma unroll
        for (int ks = 0; ks < 2; ks++) {
            bf16x8 vf[4], pf[4];
            #pragma unroll
            for (int tn = 0; tn < 4; tn++)
                vf[tn] = *(const bf16x8*)(vtb + (size_t)(tn*16 + l16) * SEQ + kb0 + ks*32 + quad*8);
            #pragma unroll
            for (int tm = 0; tm < 4; tm++)
                pf[tm] = *(const bf16x8*)&Psh[prow + tm*16 + l16][(ks*32 + quad*8) ^ rd_sw];
            #pragma unroll
            for (int tm = 0; tm < 4; tm++)
                rsacc[tm] = __builtin_amdgcn_mfma_f32_16x16x32_bf16(pf[tm], vone, rsacc[tm], 0, 0, 0);
            #pragma unroll
            for (int tm = 0; tm < 4; tm++)
                #pragma unroll
                for (int tn = 0; tn < 4; tn++)
                    o[tm][tn] = __builtin_amdgcn_mfma_f32_16x16x32_bf16(pf[tm], vf[tn], o[tm][tn], 0, 0, 0);
        }
    }

    __syncthreads();                       // all P reads done -> safe to overlay
    if (w) {
        #pragma unroll
        for (int tm = 0; tm < 4; tm++) {
            #pragma unroll
            for (int tn = 0; tn < 4; tn++)
                #pragma unroll
                for (int r = 0; r < 4; r++)
                    Ored[(w-1)*64 + tm*16 + quad*4 + r][tn*16 + l16] = o[tm][tn][r];
            if (l16 == 0)
                #pragma unroll
                for (int r = 0; r < 4; r++)
                    rsred[(w-1)*64 + tm*16 + quad*4 + r] = rsacc[tm][r];
        }
    }
    __syncthreads();
    if (w == 0) {
        #pragma unroll
        for (int j = 0; j < 3; j++)
            #pragma unroll
            for (int tm = 0; tm < 4; tm++) {
                #pragma unroll
                for (int tn = 0; tn < 4; tn++)
                    #pragma unroll
                    for (int r = 0; r < 4; r++)
                        o[tm][tn][r] += Ored[j*64 + tm*16 + quad*4 + r][tn*16 + l16];
                #pragma unroll
                for (int r = 0; r < 4; r++)
                    rsacc[tm][r] += rsred[j*64 + tm*16 + quad*4 + r];
            }
        #pragma unroll
        for (int tm = 0; tm < 4; tm++)
            #pragma unroll
            for (int tn = 0; tn < 4; tn++)
                #pragma unroll
                for (int r = 0; r < 4; r++) {
                    int n = q0 + tm*16 + quad*4 + r;
                    attn_out[((size_t)(bb*SEQ + n)) * DIMC + h*HD + tn*16 + l16] =
                        (bf16)(o[tm][tn][r] / (rsacc[tm][r] + 1e-6f));
                }
    }
}

// ---------------- driver ----------------
extern "C" void kernel_launch(void* const* d_in, const int* in_sizes, int n_in,
                              void* d_out, int out_size, void* d_ws, size_t ws_size,
                              hipStream_t stream) {
    const float* x      = (const float*)d_in[0];
    const float* qkv_w  = (const float*)d_in[1];
    const float* proj_w = (const float*)d_in[2];
    const float* proj_b = (const float*)d_in[3];
    const float* alpha  = (const float*)d_in[4];
    const float* beta   = (const float*)d_in[5];
    const float* gamma  = (const float*)d_in[6];
    const float* ln1_w  = (const float*)d_in[7];
    const float* ln1_b  = (const float*)d_in[8];
    const float* ln2_w  = (const float*)d_in[9];
    const float* ln2_b  = (const float*)d_in[10];
    const float* w1     = (const float*)d_in[11];
    const float* b1     = (const float*)d_in[12];
    const float* w2     = (const float*)d_in[13];
    const float* b2     = (const float*)d_in[14];
    float* out = (float*)d_out;           // fp32 output; also doubles as x1 buffer

    // ws layout (bytes):
    //   [0, 3538944)             bf16 weights: qkv_w(442368) proj_w(147456) w1(589824) w2(589824)
    //   [3538944, 9830400)       h (TC bf16) — ln1 out, later ln2 out
    //   [9830400, 28704768)      qkv (3*TC bf16: q,k [B,H,N,D], v [B,H,D,N])
    //   [28704768, 34996224)     attn_o (TC bf16)
    //   m (4*TC bf16) overlays [9830400, 34996224) once qkv+attn_o are dead
    //   [34996224, 60162048)     Pm: mlp2 partials (4*TC bf16); Pp (2*TC bf16) overlays its head
    char* base = (char*)d_ws;
    bf16* wq_bf = (bf16*)base;                 // 1152x384
    bf16* wp_bf = wq_bf + 442368;              // 384x384
    bf16* w1_bf = wq_bf + 589824;              // 1536x384
    bf16* w2_bf = wq_bf + 1179648;             // 384x1536
    bf16* h      = (bf16*)(base + 3538944);
    bf16* qkv    = (bf16*)(base + 9830400);
    bf16* attn_o = (bf16*)(base + 28704768);
    bf16* m      = qkv;                        // overlays qkv+attn_o (both dead by mlp1)
    bf16* Pp     = (bf16*)(base + 34996224);   // 2*TC (proj split-K partials)
    bf16* Pm     = (bf16*)(base + 34996224);   // 4*TC (mlp2 split-K partials; Pp dead)

    cvt_all<<<1728, 256, 0, stream>>>(qkv_w, proj_w, w1, w2, wq_bf);
    ln_kernel<<<T_TOK/4, 256, 0, stream>>>(x, ln1_w, ln1_b, h);
    gemm_bt<EPI_QKV, 384, 1, bf16><<<dim3(9, 64, 1), 256, 0, stream>>>(
        h, wq_bf, nullptr, qkv, T_TOK, 1152);
    attn_kernel<<<768, 256, 0, stream>>>(
        qkv, qkv + TC, qkv + 2*TC, alpha, beta, gamma, attn_o);
    gemm_bt<EPI_NONE, 384, 2, bf16><<<dim3(3, 64, 2), 256, 0, stream>>>(
        attn_o, wp_bf, nullptr, Pp, T_TOK, DIMC);
    ln2_fused<<<T_TOK/4, 256, 0, stream>>>(x, Pp, Pp + TC, proj_b, ln2_w, ln2_b, out, h);
    gemm_bt<EPI_GELU, 384, 1, bf16><<<dim3(12, 64, 1), 256, 0, stream>>>(
        h, w1_bf, b1, m, T_TOK, MLPD);
    gemm_bt<EPI_NONE, 1536, 4, bf16><<<dim3(3, 64, 4), 256, 0, stream>>>(
        m, w2_bf, nullptr, Pm, T_TOK, DIMC);
    reduce4<<<TC/4/256, 256, 0, stream>>>(out, Pm, Pm + TC, Pm + 2*TC, Pm + 3*TC, b2);
}